// Round 10
// baseline (416.809 us; speedup 1.0000x reference)
//
#include <hip/hip_runtime.h>
#include <hip/hip_bf16.h>
#include <cstdint>
#include <cstddef>

// ---------------------------------------------------------------------------
// STGNN forward. Round 15 = R14 with the bucket-build duplication bug fixed.
//  - R14 failed correctness (absmax 0.242): grid-stride ranged build with
//    gridDim.x=391 not divisible by 8 -> blocks 384-390 (j=48==nb) replayed
//    the same edge sequence as j=0 blocks from iteration 2 on -> duplicate
//    bucket entries for ranges 0-6. Fix: drop remainder blocks (guard
//    blockIdx.x >= (gridDim.x>>3)*8 in the y==8 branch).
//  - Structure unchanged from R14: 5 launches; build overlapped with
//    pretransform GEMMs; memset folded into prep_all; hot loops R13-verbatim.
// ---------------------------------------------------------------------------

#define LRELU_SLOPE 0.2f
#define CAP 64
#define NRANGE 8

typedef __attribute__((ext_vector_type(8))) short short8;
typedef __attribute__((ext_vector_type(4))) float floatx4;

__device__ __forceinline__ float bf2f(ushort u) {
    union { unsigned int u32; float f; } v; v.u32 = ((unsigned int)u) << 16; return v.f;
}
__device__ __forceinline__ ushort f2bf(float x) {
    union { float f; unsigned int u; } v; v.f = x;
    unsigned int r = (v.u + 0x7FFFu + ((v.u >> 16) & 1u)) >> 16;
    return (ushort)r;
}

// ---- prep_all: casts | 6x wtrans | fold_ct | counter zero, one grid --------
__global__ __launch_bounds__(256) void prep_all(
    const float* __restrict__ xt, ushort* __restrict__ xtb,
    const float* __restrict__ xc, ushort* __restrict__ xcb,
    const float* __restrict__ Wt,  ushort* __restrict__ WtT,
    const float* __restrict__ Wc,  ushort* __restrict__ WcT,
    const float* __restrict__ W1,  ushort* __restrict__ W1T,
    const float* __restrict__ W2,  ushort* __restrict__ W2T,
    const float* __restrict__ W3,  ushort* __restrict__ W3T,
    const float* __restrict__ W4,  ushort* __restrict__ W4T,
    const float* __restrict__ Wcd, const float* __restrict__ adc,
    float* __restrict__ wfold, int* __restrict__ cnt0,
    int s0, int s1, int s2, int s3, int s4, int s5, int s6, int s7, int s8,
    int s9)
{
    const int idx = blockIdx.x * blockDim.x + threadIdx.x;
    if (idx < s0) {                       // x_target: float4 -> ushort4
        float4 v = ((const float4*)xt)[idx];
        ushort4 o;
        o.x = f2bf(v.x); o.y = f2bf(v.y); o.z = f2bf(v.z); o.w = f2bf(v.w);
        ((ushort4*)xtb)[idx] = o;
    } else if (idx < s1) {                // x_context
        const int i = idx - s0;
        float4 v = ((const float4*)xc)[i];
        ushort4 o;
        o.x = f2bf(v.x); o.y = f2bf(v.y); o.z = f2bf(v.z); o.w = f2bf(v.w);
        ((ushort4*)xcb)[i] = o;
    } else if (idx < s2) {                // Wt [128][256]
        const int i = idx - s1, k = i >> 8, n = i & 255;
        WtT[n * 128 + k] = f2bf(Wt[i]);
    } else if (idx < s3) {                // Wc [64][256]
        const int i = idx - s2, k = i >> 8, n = i & 255;
        WcT[n * 64 + k] = f2bf(Wc[i]);
    } else if (idx < s4) {                // W_s2d [256][256]
        const int i = idx - s3, k = i >> 8, n = i & 255;
        W1T[n * 256 + k] = f2bf(W1[i]);
    } else if (idx < s5) {                // W_d2s
        const int i = idx - s4, k = i >> 8, n = i & 255;
        W2T[n * 256 + k] = f2bf(W2[i]);
    } else if (idx < s6) {                // W_ct_src
        const int i = idx - s5, k = i >> 8, n = i & 255;
        W3T[n * 256 + k] = f2bf(W3[i]);
    } else if (idx < s7) {                // W_out
        const int i = idx - s6, k = i >> 8, n = i & 255;
        W4T[n * 256 + k] = f2bf(W4[i]);
    } else if (idx < s8) {                // fold_ct: wfold[k,h]
        const int i = idx - s7, k = i >> 2, h = i & 3;
        float s = 0.f;
#pragma unroll 8
        for (int c = 0; c < 64; ++c)
            s += Wcd[(size_t)k * 256 + h * 64 + c] * adc[h * 64 + c];
        wfold[i] = s;
    } else if (idx < s9) {                // zero cntA|cntB|cntC (contiguous)
        cnt0[idx - s8] = 0;
    }
}

// -------- bf16 MFMA GEMM core, 128x64 tile, double-buffered pipeline --------
// (R13 verbatim.) 4 waves; wave w owns rows 32w..32w+31; one barrier/K-step.
__device__ __forceinline__ void gemm_core(
    const ushort* __restrict__ A, const ushort* __restrict__ Bt,
    const float* __restrict__ bias, float* __restrict__ Cf,
    ushort* __restrict__ Cb, int M, int K, int do_relu,
    const float* __restrict__ attS, const float* __restrict__ attD,
    float* __restrict__ aSo, float* __restrict__ aDo,
    int row0, int col0)
{
    __shared__ short As[2][128][40];  // +8 pad
    __shared__ short Bs[2][64][40];
    const int tid  = threadIdx.x;
    const int ra = tid >> 1;            // A stage: 2 threads/row, 16 cols each
    const int ka = (tid & 1) * 16;
    const int rb = tid >> 2;            // B stage: 4 threads/row, 8 cols each
    const int kb = (tid & 3) * 8;
    const int w    = tid >> 6;
    const int lane = tid & 63;
    const int cix  = lane & 15;
    const int ksel = (lane >> 4) * 8;
    const bool arow_ok = (row0 + ra < M);
    const ushort* aptr = A + (size_t)(row0 + ra) * K + ka;
    const ushort* bptr = Bt + (size_t)(col0 + rb) * K + kb;

    floatx4 acc[2][4];
#pragma unroll
    for (int r = 0; r < 2; ++r)
#pragma unroll
        for (int c = 0; c < 4; ++c) acc[r][c] = (floatx4){0.f, 0.f, 0.f, 0.f};

    // prologue: stage tile 0
    short8 sa0 = {0,0,0,0,0,0,0,0}, sa1 = sa0, sb;
    if (arow_ok) { sa0 = *(const short8*)aptr; sa1 = *(const short8*)(aptr + 8); }
    sb = *(const short8*)bptr;
    *(short8*)&As[0][ra][ka]     = sa0;
    *(short8*)&As[0][ra][ka + 8] = sa1;
    *(short8*)&Bs[0][rb][kb]     = sb;
    __syncthreads();

    int cur = 0;
    for (int k0 = 0; k0 < K; k0 += 32) {
        const bool more = (k0 + 32 < K);
        if (more) {                       // issue t+1 loads (hide under MFMA)
            if (arow_ok) {
                sa0 = *(const short8*)(aptr + k0 + 32);
                sa1 = *(const short8*)(aptr + k0 + 40);
            }
            sb = *(const short8*)(bptr + k0 + 32);
        }
        const short8 af0 = *(const short8*)&As[cur][32 * w + cix][ksel];
        const short8 af1 = *(const short8*)&As[cur][32 * w + 16 + cix][ksel];
#pragma unroll
        for (int c = 0; c < 4; ++c) {
            const short8 bf = *(const short8*)&Bs[cur][16 * c + cix][ksel];
            acc[0][c] = __builtin_amdgcn_mfma_f32_16x16x32_bf16(af0, bf, acc[0][c], 0, 0, 0);
            acc[1][c] = __builtin_amdgcn_mfma_f32_16x16x32_bf16(af1, bf, acc[1][c], 0, 0, 0);
        }
        if (more) {                       // write staged regs to the OTHER buf
            *(short8*)&As[cur ^ 1][ra][ka]     = sa0;
            *(short8*)&As[cur ^ 1][ra][ka + 8] = sa1;
            *(short8*)&Bs[cur ^ 1][rb][kb]     = sb;
        }
        __syncthreads();
        cur ^= 1;
    }

#pragma unroll
    for (int r = 0; r < 2; ++r) {
        const int rbase = row0 + 32 * w + 16 * r + (lane >> 4) * 4;
#pragma unroll
        for (int c = 0; c < 4; ++c) {
            const int col = col0 + 16 * c + cix;
            const float bv = bias ? bias[col] : 0.f;
#pragma unroll
            for (int i = 0; i < 4; ++i) {
                const int row = rbase + i;
                if (row < M) {
                    float v = acc[r][c][i] + bv;
                    if (do_relu) v = fmaxf(v, 0.f);
                    const size_t off = (size_t)row * 256 + col;
                    if (Cf) Cf[off] = v;
                    if (Cb) Cb[off] = f2bf(v);
                }
            }
        }
    }

    // fused per-row attention dots (raw fp32 acc, pre-bias/relu)
    if (attS) {
        float sA[2][4], sD[2][4];
#pragma unroll
        for (int r = 0; r < 2; ++r)
#pragma unroll
            for (int i = 0; i < 4; ++i) { sA[r][i] = 0.f; sD[r][i] = 0.f; }
#pragma unroll
        for (int c = 0; c < 4; ++c) {
            const float as_v = attS[col0 + 16 * c + cix];
            const float ad_v = attD ? attD[col0 + 16 * c + cix] : 0.f;
#pragma unroll
            for (int r = 0; r < 2; ++r)
#pragma unroll
                for (int i = 0; i < 4; ++i) {
                    sA[r][i] += acc[r][c][i] * as_v;
                    sD[r][i] += acc[r][c][i] * ad_v;
                }
        }
#pragma unroll
        for (int off = 1; off < 16; off <<= 1) {
#pragma unroll
            for (int r = 0; r < 2; ++r)
#pragma unroll
                for (int i = 0; i < 4; ++i) {
                    sA[r][i] += __shfl_xor(sA[r][i], off);
                    sD[r][i] += __shfl_xor(sD[r][i], off);
                }
        }
        if (cix == 0) {
            const int head = col0 >> 6;
#pragma unroll
            for (int r = 0; r < 2; ++r) {
                const int rbase = row0 + 32 * w + 16 * r + (lane >> 4) * 4;
#pragma unroll
                for (int i = 0; i < 4; ++i) {
                    const int row = rbase + i;
                    if (row < M) {
                        aSo[(size_t)row * 4 + head] = sA[r][i];
                        if (aDo) aDo[(size_t)row * 4 + head] = sD[r][i];
                    }
                }
            }
        }
    }
}

// ---- standalone GEMM (final linear): grid (M/128, 4) -----------------------
__global__ __launch_bounds__(256) void gemm_bf16(
    const ushort* __restrict__ A, const ushort* __restrict__ Bt,
    const float* __restrict__ bias, float* __restrict__ Cf,
    ushort* __restrict__ Cb, int M, int K, int do_relu)
{
    const int row0 = blockIdx.x * 128;
    if (row0 >= M) return;
    gemm_core(A, Bt, bias, Cf, Cb, M, K, do_relu,
              nullptr, nullptr, nullptr, nullptr, row0, blockIdx.y * 64);
}

// ---- pretransforms + bucket build in ONE launch ----------------------------
// y<4: target GEMM (K=128) | y<8: context GEMM (K=64) | y==8: bucket build
// (grid-stride ranged form; uses only the first (gridDim.x>>3)*8 blocks so
// every (j, range) pair is unique -- R14's remainder blocks duplicated edges).
__global__ __launch_bounds__(256) void gemm_pre2_build(
    const ushort* __restrict__ xtb, const ushort* __restrict__ WtT,
    const float* __restrict__ bt, ushort* __restrict__ htb, int NT,
    const ushort* __restrict__ xcb, const ushort* __restrict__ WcT,
    const float* __restrict__ bc, ushort* __restrict__ hcb, int NC,
    const int* __restrict__ tt_src, const int* __restrict__ tt_dst, int E_tt,
    const int* __restrict__ ct_src, const int* __restrict__ ct_dst, int E_ct,
    int RS,
    int* __restrict__ cntA, int* __restrict__ bktA,
    int* __restrict__ cntB, int* __restrict__ bktB,
    int* __restrict__ cntC, int* __restrict__ bktC)
{
    const int y = blockIdx.y;
    if (y == 8) {
        const int nb = gridDim.x >> 3;           // full groups of NRANGE
        if (blockIdx.x >= nb * NRANGE) return;   // drop remainder (bug fix)
        const int range = blockIdx.x & (NRANGE - 1);
        const int lo = range * RS, hi = lo + RS;
        const int j  = blockIdx.x >> 3;          // j in [0, nb)
        const int stride = nb * 256;
        for (int e = j * 256 + threadIdx.x; e < E_tt; e += stride) {
            const int s = tt_src[e], d = tt_dst[e];
            if (d >= lo && d < hi) {
                const int pa = atomicAdd(&cntA[d], 1);
                if (pa < CAP) bktA[(size_t)d * CAP + pa] = s;
            }
            if (s >= lo && s < hi) {
                const int pb = atomicAdd(&cntB[s], 1);
                if (pb < CAP) bktB[(size_t)s * CAP + pb] = d;
            }
        }
        for (int e = j * 256 + threadIdx.x; e < E_ct; e += stride) {
            const int s = ct_src[e], d = ct_dst[e];
            if (d >= lo && d < hi) {
                const int p = atomicAdd(&cntC[d], 1);
                if (p < CAP) bktC[(size_t)d * CAP + p] = s;
            }
        }
        return;
    }
    const int row0 = blockIdx.x * 128;
    if (y < 4) {
        if (row0 >= NT) return;
        gemm_core(xtb, WtT, bt, nullptr, htb, NT, 128, 1,
                  nullptr, nullptr, nullptr, nullptr, row0, y * 64);
    } else {
        if (row0 >= NC) return;
        gemm_core(xcb, WcT, bc, nullptr, hcb, NC, 64, 1,
                  nullptr, nullptr, nullptr, nullptr, row0, (y - 4) * 64);
    }
}

// ---- merged projections: y<4 s2d | y<8 d2s | y<12 ct-src | y==12 alpha -----
__global__ __launch_bounds__(256) void gemm_proj3(
    const ushort* __restrict__ htb, const ushort* __restrict__ hcb,
    const ushort* __restrict__ W1T, const ushort* __restrict__ W2T,
    const ushort* __restrict__ W3T,
    ushort* __restrict__ Pb1, ushort* __restrict__ Pb2, ushort* __restrict__ PSb,
    const float* __restrict__ as1, const float* __restrict__ ad1,
    const float* __restrict__ as2, const float* __restrict__ ad2,
    const float* __restrict__ asc,
    float* __restrict__ aS1, float* __restrict__ aD1,
    float* __restrict__ aS2, float* __restrict__ aD2,
    float* __restrict__ aSc,
    const float* __restrict__ wfold, float* __restrict__ aDc,
    int NT, int NC)
{
    const int y = blockIdx.y;
    if (y == 12) {
        // alpha_from_fold, grid-strided: aDc[n,h] = htb[n,:] . wfold[:,h]
        __shared__ float wf[1024];
        const int tid = threadIdx.x;
        *(float4*)&wf[tid * 4] = *(const float4*)&wfold[tid * 4];
        __syncthreads();
        const int total = NT * 4;
        for (int base = blockIdx.x * 256; base < total; base += gridDim.x * 256) {
            const int idx = base + tid;
            if (idx < total) {
                const int n = idx >> 2, h = idx & 3;
                const ushort* row = htb + (size_t)n * 256;
                float s = 0.f;
#pragma unroll
                for (int k = 0; k < 256; k += 4) {
                    ushort4 r4 = *(const ushort4*)(row + k);
                    s += bf2f(r4.x) * wf[(k + 0) * 4 + h] + bf2f(r4.y) * wf[(k + 1) * 4 + h]
                       + bf2f(r4.z) * wf[(k + 2) * 4 + h] + bf2f(r4.w) * wf[(k + 3) * 4 + h];
                }
                aDc[idx] = s;
            }
        }
        return;
    }
    const int row0 = blockIdx.x * 128;
    if (y < 4) {
        if (row0 >= NT) return;
        gemm_core(htb, W1T, nullptr, nullptr, Pb1, NT, 256, 0,
                  as1, ad1, aS1, aD1, row0, y * 64);
    } else if (y < 8) {
        if (row0 >= NT) return;
        gemm_core(htb, W2T, nullptr, nullptr, Pb2, NT, 256, 0,
                  as2, ad2, aS2, aD2, row0, (y - 4) * 64);
    } else {
        if (row0 >= NC) return;
        gemm_core(hcb, W3T, nullptr, nullptr, PSb, NC, 256, 0,
                  asc, nullptr, aSc, nullptr, row0, (y - 8) * 64);
    }
}

// ---- one GAT accumulation phase (R7 verbatim; inlined 3x in fused gather) --
__device__ __forceinline__ void gat_phase(
    int n, int h, int c4,
    const int* __restrict__ cnt, const int* __restrict__ bkt,
    const float* __restrict__ aS, const float* __restrict__ aD,
    const ushort* __restrict__ X, const float* __restrict__ bias,
    float scale, int has_self, float4& out)
{
    const float aDn = aD[(size_t)n * 4 + h];
    float4 f = {0.f, 0.f, 0.f, 0.f};
    float den = 0.f;
    if (has_self) {
        float a = aS[(size_t)n * 4 + h] + aDn;
        a = (a >= 0.f) ? a : LRELU_SLOPE * a;
        const float w = __expf(a);
        const ushort4 x = *(const ushort4*)(X + (size_t)n * 256 + c4);
        f.x = w * bf2f(x.x); f.y = w * bf2f(x.y);
        f.z = w * bf2f(x.z); f.w = w * bf2f(x.w);
        den = w;
    }
    const int deg = min(cnt[n], CAP);
    const int* b = bkt + (size_t)n * CAP;
    int i = 0;
    for (; i + 4 <= deg; i += 4) {
        const int s0 = b[i], s1 = b[i + 1], s2 = b[i + 2], s3 = b[i + 3];
        float a0 = aS[(size_t)s0 * 4 + h] + aDn;
        float a1 = aS[(size_t)s1 * 4 + h] + aDn;
        float a2 = aS[(size_t)s2 * 4 + h] + aDn;
        float a3 = aS[(size_t)s3 * 4 + h] + aDn;
        a0 = (a0 >= 0.f) ? a0 : LRELU_SLOPE * a0;
        a1 = (a1 >= 0.f) ? a1 : LRELU_SLOPE * a1;
        a2 = (a2 >= 0.f) ? a2 : LRELU_SLOPE * a2;
        a3 = (a3 >= 0.f) ? a3 : LRELU_SLOPE * a3;
        const float w0 = __expf(a0), w1 = __expf(a1);
        const float w2 = __expf(a2), w3 = __expf(a3);
        const ushort4 x0 = *(const ushort4*)(X + (size_t)s0 * 256 + c4);
        const ushort4 x1 = *(const ushort4*)(X + (size_t)s1 * 256 + c4);
        const ushort4 x2 = *(const ushort4*)(X + (size_t)s2 * 256 + c4);
        const ushort4 x3 = *(const ushort4*)(X + (size_t)s3 * 256 + c4);
        f.x += w0 * bf2f(x0.x) + w1 * bf2f(x1.x) + w2 * bf2f(x2.x) + w3 * bf2f(x3.x);
        f.y += w0 * bf2f(x0.y) + w1 * bf2f(x1.y) + w2 * bf2f(x2.y) + w3 * bf2f(x3.y);
        f.z += w0 * bf2f(x0.z) + w1 * bf2f(x1.z) + w2 * bf2f(x2.z) + w3 * bf2f(x3.z);
        f.w += w0 * bf2f(x0.w) + w1 * bf2f(x1.w) + w2 * bf2f(x2.w) + w3 * bf2f(x3.w);
        den += w0 + w1 + w2 + w3;
    }
    for (; i < deg; ++i) {
        const int s = b[i];
        float a = aS[(size_t)s * 4 + h] + aDn;
        a = (a >= 0.f) ? a : LRELU_SLOPE * a;
        const float w = __expf(a);
        const ushort4 x = *(const ushort4*)(X + (size_t)s * 256 + c4);
        f.x += w * bf2f(x.x); f.y += w * bf2f(x.y);
        f.z += w * bf2f(x.z); f.w += w * bf2f(x.w);
        den += w;
    }
    const float inv = 1.f / fmaxf(den, 1e-16f);
    const float4 bv = *(const float4*)(bias + c4);
    out.x += scale * (f.x * inv + bv.x);
    out.y += scale * (f.y * inv + bv.y);
    out.z += scale * (f.z * inv + bv.z);
    out.w += scale * (f.w * inv + bv.w);
}

// ---- fused gather: all 3 GATs + skip + relu + bf16 cast, one wave/node -----
__global__ __launch_bounds__(256) void gat_gather_fused(
    const int* __restrict__ cntA, const int* __restrict__ bktA,
    const float* __restrict__ aS1, const float* __restrict__ aD1,
    const ushort* __restrict__ P1, const float* __restrict__ b1,
    const int* __restrict__ cntB, const int* __restrict__ bktB,
    const float* __restrict__ aS2, const float* __restrict__ aD2,
    const ushort* __restrict__ P2, const float* __restrict__ b2,
    const int* __restrict__ cntC, const int* __restrict__ bktC,
    const float* __restrict__ aSc, const float* __restrict__ aDc,
    const ushort* __restrict__ Pc, const float* __restrict__ b3,
    ushort* __restrict__ htb, int N)
{
    const int n = blockIdx.x * 4 + (threadIdx.x >> 6);
    if (n >= N) return;
    const int lane = threadIdx.x & 63;
    const int h  = lane >> 4;          // 16 lanes per head
    const int c4 = lane << 2;          // channel base, 0..252

    float4 out = {0.f, 0.f, 0.f, 0.f};
    gat_phase(n, h, c4, cntA, bktA, aS1, aD1, P1, b1, 0.25f, 1, out);
    gat_phase(n, h, c4, cntB, bktB, aS2, aD2, P2, b2, 0.25f, 1, out);
    gat_phase(n, h, c4, cntC, bktC, aSc, aDc, Pc, b3, 0.50f, 0, out);

    ushort* hp = htb + (size_t)n * 256 + c4;
    const ushort4 hb = *(const ushort4*)hp;
    ushort4 o;
    o.x = f2bf(fmaxf(out.x + bf2f(hb.x), 0.f));
    o.y = f2bf(fmaxf(out.y + bf2f(hb.y), 0.f));
    o.z = f2bf(fmaxf(out.z + bf2f(hb.z), 0.f));
    o.w = f2bf(fmaxf(out.w + bf2f(hb.w), 0.f));
    *(ushort4*)hp = o;
}

// ---------------------------------------------------------------------------
extern "C" void kernel_launch(void* const* d_in, const int* in_sizes, int n_in,
                              void* d_out, int out_size, void* d_ws, size_t ws_size,
                              hipStream_t stream)
{
    const int NT   = in_sizes[0] / 128;
    const int NC   = in_sizes[1] / 64;
    const int E_TT = in_sizes[2] / 2;
    const int E_CT = in_sizes[3];

    const float* x_target = (const float*)d_in[0];
    const float* x_context= (const float*)d_in[1];
    const int*   ei_tt    = (const int*)d_in[2];
    const int*   ei_ct_src= (const int*)d_in[3];
    const int*   ei_ct_dst= (const int*)d_in[4];
    const float* Wt   = (const float*)d_in[5];
    const float* bt   = (const float*)d_in[6];
    const float* Wc   = (const float*)d_in[7];
    const float* bc   = (const float*)d_in[8];
    const float* W_s2d  = (const float*)d_in[9];
    const float* as_s2d = (const float*)d_in[10];
    const float* ad_s2d = (const float*)d_in[11];
    const float* b_s2d  = (const float*)d_in[12];
    const float* W_d2s  = (const float*)d_in[13];
    const float* as_d2s = (const float*)d_in[14];
    const float* ad_d2s = (const float*)d_in[15];
    const float* b_d2s  = (const float*)d_in[16];
    const float* W_ct_src = (const float*)d_in[17];
    const float* W_ct_dst = (const float*)d_in[18];
    const float* as_ct  = (const float*)d_in[19];
    const float* ad_ct  = (const float*)d_in[20];
    const float* b_ct   = (const float*)d_in[21];
    const float* W_out  = (const float*)d_in[22];
    const float* b_out  = (const float*)d_in[23];
    float* out = (float*)d_out;

    const int* tt_src = ei_tt;
    const int* tt_dst = ei_tt + E_TT;

    // ---- workspace carve-up (units: fp32 slots) ----
    float* ws = (float*)d_ws;
    size_t o = 0;
    ushort* htb = (ushort*)(ws + o);   o += (size_t)NT * 128;   // NT*256 bf16
    ushort* Pb1 = (ushort*)(ws + o);   o += (size_t)NT * 128;
    ushort* Pb2 = (ushort*)(ws + o);   o += (size_t)NT * 128;
    ushort* hcb = (ushort*)(ws + o);   o += (size_t)NC * 128;
    ushort* PSb = (ushort*)(ws + o);   o += (size_t)NC * 128;
    ushort* xtb = (ushort*)(ws + o);   o += (size_t)NT * 64;    // NT*128 bf16
    ushort* xcb = (ushort*)(ws + o);   o += (size_t)NC * 32;
    int* bktA = (int*)(ws + o);        o += (size_t)NT * CAP;   // int payload
    int* bktB = (int*)(ws + o);        o += (size_t)NT * CAP;
    int* bktC = (int*)(ws + o);        o += (size_t)NT * CAP;
    float* aS1 = ws + o;               o += (size_t)NT * 4;
    float* aD1 = ws + o;               o += (size_t)NT * 4;
    float* aS2 = ws + o;               o += (size_t)NT * 4;
    float* aD2 = ws + o;               o += (size_t)NT * 4;
    float* aSc = ws + o;               o += (size_t)NT * 4;     // used: NC*4
    float* aDc = ws + o;               o += (size_t)NT * 4;
    int*   cntA = (int*)(ws + o);      o += (size_t)NT;
    int*   cntB = (int*)(ws + o);      o += (size_t)NT;
    int*   cntC = (int*)(ws + o);      o += (size_t)NT;
    float* wfold = ws + o;             o += 1024;
    ushort* WtT   = (ushort*)(ws + o); o += 128 * 256 / 2;
    ushort* WcT   = (ushort*)(ws + o); o += 64 * 256 / 2;
    ushort* Ws2dT = (ushort*)(ws + o); o += 256 * 256 / 2;
    ushort* Wd2sT = (ushort*)(ws + o); o += 256 * 256 / 2;
    ushort* WctsT = (ushort*)(ws + o); o += 256 * 256 / 2;
    ushort* WoutT = (ushort*)(ws + o); o += 256 * 256 / 2;
    (void)ws_size; (void)n_in; (void)out_size;

    const dim3 blk(256);
    const int gGat = (NT + 3) / 4;
    const int RS = (NT + NRANGE - 1) / NRANGE;   // node-range size per XCD
    const int gxT = (NT + 127) / 128;            // 128-row GEMM tiles over NT

    // 1) prep: casts + 6 wtrans + fold_ct + counter zero, one launch
    const int s0 = NT * 32;            // x_target float4 count
    const int s1 = s0 + NC * 16;       // x_context
    const int s2 = s1 + 128 * 256;     // Wt
    const int s3 = s2 + 64 * 256;      // Wc
    const int s4 = s3 + 65536;         // W_s2d
    const int s5 = s4 + 65536;         // W_d2s
    const int s6 = s5 + 65536;         // W_ct_src
    const int s7 = s6 + 65536;         // W_out
    const int s8 = s7 + 1024;          // fold_ct
    const int s9 = s8 + NT * 3;        // counter zero (cntA|cntB|cntC)
    hipLaunchKernelGGL(prep_all, dim3((s9 + 255) / 256), blk, 0, stream,
                       x_target, xtb, x_context, xcb,
                       Wt, WtT, Wc, WcT, W_s2d, Ws2dT, W_d2s, Wd2sT,
                       W_ct_src, WctsT, W_out, WoutT,
                       W_ct_dst, ad_ct, wfold, cntA,
                       s0, s1, s2, s3, s4, s5, s6, s7, s8, s9);

    // 2) pretransforms + bucket build (overlapped), one launch
    hipLaunchKernelGGL(gemm_pre2_build, dim3(gxT, 9), blk, 0, stream,
                       xtb, WtT, bt, htb, NT, xcb, WcT, bc, hcb, NC,
                       tt_src, tt_dst, E_TT, ei_ct_src, ei_ct_dst, E_CT, RS,
                       cntA, bktA, cntB, bktB, cntC, bktC);

    // 3) projections + attn dots + ct-dst alphas, one launch
    hipLaunchKernelGGL(gemm_proj3, dim3(gxT, 13), blk, 0, stream,
                       htb, hcb, Ws2dT, Wd2sT, WctsT, Pb1, Pb2, PSb,
                       as_s2d, ad_s2d, as_d2s, ad_d2s, as_ct,
                       aS1, aD1, aS2, aD2, aSc, wfold, aDc, NT, NC);

    // 4) single fused gather: s2d + d2s + ct + skip + relu + bf16 cast
    hipLaunchKernelGGL(gat_gather_fused, dim3(gGat), blk, 0, stream,
                       cntA, bktA, aS1, aD1, Pb1, b_s2d,
                       cntB, bktB, aS2, aD2, Pb2, b_d2s,
                       cntC, bktC, aSc, aDc, PSb, b_ct,
                       htb, NT);

    // 5) final linear
    hipLaunchKernelGGL(gemm_bf16, dim3(gxT, 4), blk, 0, stream,
                       htb, WoutT, b_out, out, nullptr, NT, 256, 0);
}

// Round 11
// 404.636 us; speedup vs baseline: 1.0301x; 1.0301x over previous
//
#include <hip/hip_runtime.h>
#include <hip/hip_bf16.h>
#include <cstdint>
#include <cstddef>

// ---------------------------------------------------------------------------
// STGNN forward. Round 16: best-of-measured hybrid.
//  - R15 post-mortem: build-under-GEMM overlap HURT (404.5->416.8): merged
//    kernel = max(GEMM, build), and build slowed (384 shared blocks vs 1024
//    dedicated). Revert build to standalone R11/R13 form.
//  - Keep R15's harmless parts: counter-zero folded into prep_all (one fewer
//    stream op), grid-strided alpha segment in proj3 (no dead blocks).
//  - Hot loops byte-identical to their best-measured variants:
//    gather = R7 form (104us, scatter-BW floor), gemm_core = R13 pipelined
//    128x64, build = R11 1024-block ranged form.
//  - 6 stream ops: prep | build | pre2 | proj3 | gather | final.
// ---------------------------------------------------------------------------

#define LRELU_SLOPE 0.2f
#define CAP 64
#define NRANGE 8

typedef __attribute__((ext_vector_type(8))) short short8;
typedef __attribute__((ext_vector_type(4))) float floatx4;

__device__ __forceinline__ float bf2f(ushort u) {
    union { unsigned int u32; float f; } v; v.u32 = ((unsigned int)u) << 16; return v.f;
}
__device__ __forceinline__ ushort f2bf(float x) {
    union { float f; unsigned int u; } v; v.f = x;
    unsigned int r = (v.u + 0x7FFFu + ((v.u >> 16) & 1u)) >> 16;
    return (ushort)r;
}

// ---- prep_all: casts | 6x wtrans | fold_ct | counter zero, one grid --------
__global__ __launch_bounds__(256) void prep_all(
    const float* __restrict__ xt, ushort* __restrict__ xtb,
    const float* __restrict__ xc, ushort* __restrict__ xcb,
    const float* __restrict__ Wt,  ushort* __restrict__ WtT,
    const float* __restrict__ Wc,  ushort* __restrict__ WcT,
    const float* __restrict__ W1,  ushort* __restrict__ W1T,
    const float* __restrict__ W2,  ushort* __restrict__ W2T,
    const float* __restrict__ W3,  ushort* __restrict__ W3T,
    const float* __restrict__ W4,  ushort* __restrict__ W4T,
    const float* __restrict__ Wcd, const float* __restrict__ adc,
    float* __restrict__ wfold, int* __restrict__ cnt0,
    int s0, int s1, int s2, int s3, int s4, int s5, int s6, int s7, int s8,
    int s9)
{
    const int idx = blockIdx.x * blockDim.x + threadIdx.x;
    if (idx < s0) {                       // x_target: float4 -> ushort4
        float4 v = ((const float4*)xt)[idx];
        ushort4 o;
        o.x = f2bf(v.x); o.y = f2bf(v.y); o.z = f2bf(v.z); o.w = f2bf(v.w);
        ((ushort4*)xtb)[idx] = o;
    } else if (idx < s1) {                // x_context
        const int i = idx - s0;
        float4 v = ((const float4*)xc)[i];
        ushort4 o;
        o.x = f2bf(v.x); o.y = f2bf(v.y); o.z = f2bf(v.z); o.w = f2bf(v.w);
        ((ushort4*)xcb)[i] = o;
    } else if (idx < s2) {                // Wt [128][256]
        const int i = idx - s1, k = i >> 8, n = i & 255;
        WtT[n * 128 + k] = f2bf(Wt[i]);
    } else if (idx < s3) {                // Wc [64][256]
        const int i = idx - s2, k = i >> 8, n = i & 255;
        WcT[n * 64 + k] = f2bf(Wc[i]);
    } else if (idx < s4) {                // W_s2d [256][256]
        const int i = idx - s3, k = i >> 8, n = i & 255;
        W1T[n * 256 + k] = f2bf(W1[i]);
    } else if (idx < s5) {                // W_d2s
        const int i = idx - s4, k = i >> 8, n = i & 255;
        W2T[n * 256 + k] = f2bf(W2[i]);
    } else if (idx < s6) {                // W_ct_src
        const int i = idx - s5, k = i >> 8, n = i & 255;
        W3T[n * 256 + k] = f2bf(W3[i]);
    } else if (idx < s7) {                // W_out
        const int i = idx - s6, k = i >> 8, n = i & 255;
        W4T[n * 256 + k] = f2bf(W4[i]);
    } else if (idx < s8) {                // fold_ct: wfold[k,h]
        const int i = idx - s7, k = i >> 2, h = i & 3;
        float s = 0.f;
#pragma unroll 8
        for (int c = 0; c < 64; ++c)
            s += Wcd[(size_t)k * 256 + h * 64 + c] * adc[h * 64 + c];
        wfold[i] = s;
    } else if (idx < s9) {                // zero cntA|cntB|cntC (contiguous)
        cnt0[idx - s8] = 0;
    }
}

// ---- standalone topology bucket build: blocks [0,512) tt, [512,1024) ct ----
// (R11/R13 proven form.) XCD-range-partitioned (range = bx&7), int payload.
__global__ __launch_bounds__(256) void build_all_buckets(
    const int* __restrict__ tt_src, const int* __restrict__ tt_dst, int E_tt,
    const int* __restrict__ ct_src, const int* __restrict__ ct_dst, int E_ct,
    int RS,
    int* __restrict__ cntA, int* __restrict__ bktA,
    int* __restrict__ cntB, int* __restrict__ bktB,
    int* __restrict__ cntC, int* __restrict__ bktC)
{
    const int bx = (blockIdx.x < 512) ? blockIdx.x : blockIdx.x - 512;
    const int range = bx & (NRANGE - 1);
    const int lo = range * RS, hi = lo + RS;
    const int j  = bx >> 3;                  // 64 blocks per range
    const int stride = 64 * blockDim.x;
    if (blockIdx.x < 512) {
        for (int e = j * blockDim.x + threadIdx.x; e < E_tt; e += stride) {
            const int s = tt_src[e], d = tt_dst[e];
            if (d >= lo && d < hi) {
                const int pa = atomicAdd(&cntA[d], 1);
                if (pa < CAP) bktA[(size_t)d * CAP + pa] = s;
            }
            if (s >= lo && s < hi) {
                const int pb = atomicAdd(&cntB[s], 1);
                if (pb < CAP) bktB[(size_t)s * CAP + pb] = d;
            }
        }
    } else {
        for (int e = j * blockDim.x + threadIdx.x; e < E_ct; e += stride) {
            const int s = ct_src[e], d = ct_dst[e];
            if (d >= lo && d < hi) {
                const int p = atomicAdd(&cntC[d], 1);
                if (p < CAP) bktC[(size_t)d * CAP + p] = s;
            }
        }
    }
}

// -------- bf16 MFMA GEMM core, 128x64 tile, double-buffered pipeline --------
// (R13 verbatim.) 4 waves; wave w owns rows 32w..32w+31; one barrier/K-step.
__device__ __forceinline__ void gemm_core(
    const ushort* __restrict__ A, const ushort* __restrict__ Bt,
    const float* __restrict__ bias, float* __restrict__ Cf,
    ushort* __restrict__ Cb, int M, int K, int do_relu,
    const float* __restrict__ attS, const float* __restrict__ attD,
    float* __restrict__ aSo, float* __restrict__ aDo,
    int row0, int col0)
{
    __shared__ short As[2][128][40];  // +8 pad
    __shared__ short Bs[2][64][40];
    const int tid  = threadIdx.x;
    const int ra = tid >> 1;            // A stage: 2 threads/row, 16 cols each
    const int ka = (tid & 1) * 16;
    const int rb = tid >> 2;            // B stage: 4 threads/row, 8 cols each
    const int kb = (tid & 3) * 8;
    const int w    = tid >> 6;
    const int lane = tid & 63;
    const int cix  = lane & 15;
    const int ksel = (lane >> 4) * 8;
    const bool arow_ok = (row0 + ra < M);
    const ushort* aptr = A + (size_t)(row0 + ra) * K + ka;
    const ushort* bptr = Bt + (size_t)(col0 + rb) * K + kb;

    floatx4 acc[2][4];
#pragma unroll
    for (int r = 0; r < 2; ++r)
#pragma unroll
        for (int c = 0; c < 4; ++c) acc[r][c] = (floatx4){0.f, 0.f, 0.f, 0.f};

    // prologue: stage tile 0
    short8 sa0 = {0,0,0,0,0,0,0,0}, sa1 = sa0, sb;
    if (arow_ok) { sa0 = *(const short8*)aptr; sa1 = *(const short8*)(aptr + 8); }
    sb = *(const short8*)bptr;
    *(short8*)&As[0][ra][ka]     = sa0;
    *(short8*)&As[0][ra][ka + 8] = sa1;
    *(short8*)&Bs[0][rb][kb]     = sb;
    __syncthreads();

    int cur = 0;
    for (int k0 = 0; k0 < K; k0 += 32) {
        const bool more = (k0 + 32 < K);
        if (more) {                       // issue t+1 loads (hide under MFMA)
            if (arow_ok) {
                sa0 = *(const short8*)(aptr + k0 + 32);
                sa1 = *(const short8*)(aptr + k0 + 40);
            }
            sb = *(const short8*)(bptr + k0 + 32);
        }
        const short8 af0 = *(const short8*)&As[cur][32 * w + cix][ksel];
        const short8 af1 = *(const short8*)&As[cur][32 * w + 16 + cix][ksel];
#pragma unroll
        for (int c = 0; c < 4; ++c) {
            const short8 bf = *(const short8*)&Bs[cur][16 * c + cix][ksel];
            acc[0][c] = __builtin_amdgcn_mfma_f32_16x16x32_bf16(af0, bf, acc[0][c], 0, 0, 0);
            acc[1][c] = __builtin_amdgcn_mfma_f32_16x16x32_bf16(af1, bf, acc[1][c], 0, 0, 0);
        }
        if (more) {                       // write staged regs to the OTHER buf
            *(short8*)&As[cur ^ 1][ra][ka]     = sa0;
            *(short8*)&As[cur ^ 1][ra][ka + 8] = sa1;
            *(short8*)&Bs[cur ^ 1][rb][kb]     = sb;
        }
        __syncthreads();
        cur ^= 1;
    }

#pragma unroll
    for (int r = 0; r < 2; ++r) {
        const int rbase = row0 + 32 * w + 16 * r + (lane >> 4) * 4;
#pragma unroll
        for (int c = 0; c < 4; ++c) {
            const int col = col0 + 16 * c + cix;
            const float bv = bias ? bias[col] : 0.f;
#pragma unroll
            for (int i = 0; i < 4; ++i) {
                const int row = rbase + i;
                if (row < M) {
                    float v = acc[r][c][i] + bv;
                    if (do_relu) v = fmaxf(v, 0.f);
                    const size_t off = (size_t)row * 256 + col;
                    if (Cf) Cf[off] = v;
                    if (Cb) Cb[off] = f2bf(v);
                }
            }
        }
    }

    // fused per-row attention dots (raw fp32 acc, pre-bias/relu)
    if (attS) {
        float sA[2][4], sD[2][4];
#pragma unroll
        for (int r = 0; r < 2; ++r)
#pragma unroll
            for (int i = 0; i < 4; ++i) { sA[r][i] = 0.f; sD[r][i] = 0.f; }
#pragma unroll
        for (int c = 0; c < 4; ++c) {
            const float as_v = attS[col0 + 16 * c + cix];
            const float ad_v = attD ? attD[col0 + 16 * c + cix] : 0.f;
#pragma unroll
            for (int r = 0; r < 2; ++r)
#pragma unroll
                for (int i = 0; i < 4; ++i) {
                    sA[r][i] += acc[r][c][i] * as_v;
                    sD[r][i] += acc[r][c][i] * ad_v;
                }
        }
#pragma unroll
        for (int off = 1; off < 16; off <<= 1) {
#pragma unroll
            for (int r = 0; r < 2; ++r)
#pragma unroll
                for (int i = 0; i < 4; ++i) {
                    sA[r][i] += __shfl_xor(sA[r][i], off);
                    sD[r][i] += __shfl_xor(sD[r][i], off);
                }
        }
        if (cix == 0) {
            const int head = col0 >> 6;
#pragma unroll
            for (int r = 0; r < 2; ++r) {
                const int rbase = row0 + 32 * w + 16 * r + (lane >> 4) * 4;
#pragma unroll
                for (int i = 0; i < 4; ++i) {
                    const int row = rbase + i;
                    if (row < M) {
                        aSo[(size_t)row * 4 + head] = sA[r][i];
                        if (aDo) aDo[(size_t)row * 4 + head] = sD[r][i];
                    }
                }
            }
        }
    }
}

// ---- standalone GEMM (final linear): grid (M/128, 4) -----------------------
__global__ __launch_bounds__(256) void gemm_bf16(
    const ushort* __restrict__ A, const ushort* __restrict__ Bt,
    const float* __restrict__ bias, float* __restrict__ Cf,
    ushort* __restrict__ Cb, int M, int K, int do_relu)
{
    const int row0 = blockIdx.x * 128;
    if (row0 >= M) return;
    gemm_core(A, Bt, bias, Cf, Cb, M, K, do_relu,
              nullptr, nullptr, nullptr, nullptr, row0, blockIdx.y * 64);
}

// ---- merged pretransforms: y<4 target (K=128), y>=4 context (K=64) ---------
__global__ __launch_bounds__(256) void gemm_pre2(
    const ushort* __restrict__ xtb, const ushort* __restrict__ WtT,
    const float* __restrict__ bt, ushort* __restrict__ htb, int NT,
    const ushort* __restrict__ xcb, const ushort* __restrict__ WcT,
    const float* __restrict__ bc, ushort* __restrict__ hcb, int NC)
{
    const int y = blockIdx.y;
    const int row0 = blockIdx.x * 128;
    if (y < 4) {
        if (row0 >= NT) return;
        gemm_core(xtb, WtT, bt, nullptr, htb, NT, 128, 1,
                  nullptr, nullptr, nullptr, nullptr, row0, y * 64);
    } else {
        if (row0 >= NC) return;
        gemm_core(xcb, WcT, bc, nullptr, hcb, NC, 64, 1,
                  nullptr, nullptr, nullptr, nullptr, row0, (y - 4) * 64);
    }
}

// ---- merged projections: y<4 s2d | y<8 d2s | y<12 ct-src | y==12 alpha -----
__global__ __launch_bounds__(256) void gemm_proj3(
    const ushort* __restrict__ htb, const ushort* __restrict__ hcb,
    const ushort* __restrict__ W1T, const ushort* __restrict__ W2T,
    const ushort* __restrict__ W3T,
    ushort* __restrict__ Pb1, ushort* __restrict__ Pb2, ushort* __restrict__ PSb,
    const float* __restrict__ as1, const float* __restrict__ ad1,
    const float* __restrict__ as2, const float* __restrict__ ad2,
    const float* __restrict__ asc,
    float* __restrict__ aS1, float* __restrict__ aD1,
    float* __restrict__ aS2, float* __restrict__ aD2,
    float* __restrict__ aSc,
    const float* __restrict__ wfold, float* __restrict__ aDc,
    int NT, int NC)
{
    const int y = blockIdx.y;
    if (y == 12) {
        // alpha_from_fold, grid-strided: aDc[n,h] = htb[n,:] . wfold[:,h]
        __shared__ float wf[1024];
        const int tid = threadIdx.x;
        *(float4*)&wf[tid * 4] = *(const float4*)&wfold[tid * 4];
        __syncthreads();
        const int total = NT * 4;
        for (int base = blockIdx.x * 256; base < total; base += gridDim.x * 256) {
            const int idx = base + tid;
            if (idx < total) {
                const int n = idx >> 2, h = idx & 3;
                const ushort* row = htb + (size_t)n * 256;
                float s = 0.f;
#pragma unroll
                for (int k = 0; k < 256; k += 4) {
                    ushort4 r4 = *(const ushort4*)(row + k);
                    s += bf2f(r4.x) * wf[(k + 0) * 4 + h] + bf2f(r4.y) * wf[(k + 1) * 4 + h]
                       + bf2f(r4.z) * wf[(k + 2) * 4 + h] + bf2f(r4.w) * wf[(k + 3) * 4 + h];
                }
                aDc[idx] = s;
            }
        }
        return;
    }
    const int row0 = blockIdx.x * 128;
    if (y < 4) {
        if (row0 >= NT) return;
        gemm_core(htb, W1T, nullptr, nullptr, Pb1, NT, 256, 0,
                  as1, ad1, aS1, aD1, row0, y * 64);
    } else if (y < 8) {
        if (row0 >= NT) return;
        gemm_core(htb, W2T, nullptr, nullptr, Pb2, NT, 256, 0,
                  as2, ad2, aS2, aD2, row0, (y - 4) * 64);
    } else {
        if (row0 >= NC) return;
        gemm_core(hcb, W3T, nullptr, nullptr, PSb, NC, 256, 0,
                  asc, nullptr, aSc, nullptr, row0, (y - 8) * 64);
    }
}

// ---- one GAT accumulation phase (R7 verbatim; inlined 3x in fused gather) --
__device__ __forceinline__ void gat_phase(
    int n, int h, int c4,
    const int* __restrict__ cnt, const int* __restrict__ bkt,
    const float* __restrict__ aS, const float* __restrict__ aD,
    const ushort* __restrict__ X, const float* __restrict__ bias,
    float scale, int has_self, float4& out)
{
    const float aDn = aD[(size_t)n * 4 + h];
    float4 f = {0.f, 0.f, 0.f, 0.f};
    float den = 0.f;
    if (has_self) {
        float a = aS[(size_t)n * 4 + h] + aDn;
        a = (a >= 0.f) ? a : LRELU_SLOPE * a;
        const float w = __expf(a);
        const ushort4 x = *(const ushort4*)(X + (size_t)n * 256 + c4);
        f.x = w * bf2f(x.x); f.y = w * bf2f(x.y);
        f.z = w * bf2f(x.z); f.w = w * bf2f(x.w);
        den = w;
    }
    const int deg = min(cnt[n], CAP);
    const int* b = bkt + (size_t)n * CAP;
    int i = 0;
    for (; i + 4 <= deg; i += 4) {
        const int s0 = b[i], s1 = b[i + 1], s2 = b[i + 2], s3 = b[i + 3];
        float a0 = aS[(size_t)s0 * 4 + h] + aDn;
        float a1 = aS[(size_t)s1 * 4 + h] + aDn;
        float a2 = aS[(size_t)s2 * 4 + h] + aDn;
        float a3 = aS[(size_t)s3 * 4 + h] + aDn;
        a0 = (a0 >= 0.f) ? a0 : LRELU_SLOPE * a0;
        a1 = (a1 >= 0.f) ? a1 : LRELU_SLOPE * a1;
        a2 = (a2 >= 0.f) ? a2 : LRELU_SLOPE * a2;
        a3 = (a3 >= 0.f) ? a3 : LRELU_SLOPE * a3;
        const float w0 = __expf(a0), w1 = __expf(a1);
        const float w2 = __expf(a2), w3 = __expf(a3);
        const ushort4 x0 = *(const ushort4*)(X + (size_t)s0 * 256 + c4);
        const ushort4 x1 = *(const ushort4*)(X + (size_t)s1 * 256 + c4);
        const ushort4 x2 = *(const ushort4*)(X + (size_t)s2 * 256 + c4);
        const ushort4 x3 = *(const ushort4*)(X + (size_t)s3 * 256 + c4);
        f.x += w0 * bf2f(x0.x) + w1 * bf2f(x1.x) + w2 * bf2f(x2.x) + w3 * bf2f(x3.x);
        f.y += w0 * bf2f(x0.y) + w1 * bf2f(x1.y) + w2 * bf2f(x2.y) + w3 * bf2f(x3.y);
        f.z += w0 * bf2f(x0.z) + w1 * bf2f(x1.z) + w2 * bf2f(x2.z) + w3 * bf2f(x3.z);
        f.w += w0 * bf2f(x0.w) + w1 * bf2f(x1.w) + w2 * bf2f(x2.w) + w3 * bf2f(x3.w);
        den += w0 + w1 + w2 + w3;
    }
    for (; i < deg; ++i) {
        const int s = b[i];
        float a = aS[(size_t)s * 4 + h] + aDn;
        a = (a >= 0.f) ? a : LRELU_SLOPE * a;
        const float w = __expf(a);
        const ushort4 x = *(const ushort4*)(X + (size_t)s * 256 + c4);
        f.x += w * bf2f(x.x); f.y += w * bf2f(x.y);
        f.z += w * bf2f(x.z); f.w += w * bf2f(x.w);
        den += w;
    }
    const float inv = 1.f / fmaxf(den, 1e-16f);
    const float4 bv = *(const float4*)(bias + c4);
    out.x += scale * (f.x * inv + bv.x);
    out.y += scale * (f.y * inv + bv.y);
    out.z += scale * (f.z * inv + bv.z);
    out.w += scale * (f.w * inv + bv.w);
}

// ---- fused gather: all 3 GATs + skip + relu + bf16 cast, one wave/node -----
__global__ __launch_bounds__(256) void gat_gather_fused(
    const int* __restrict__ cntA, const int* __restrict__ bktA,
    const float* __restrict__ aS1, const float* __restrict__ aD1,
    const ushort* __restrict__ P1, const float* __restrict__ b1,
    const int* __restrict__ cntB, const int* __restrict__ bktB,
    const float* __restrict__ aS2, const float* __restrict__ aD2,
    const ushort* __restrict__ P2, const float* __restrict__ b2,
    const int* __restrict__ cntC, const int* __restrict__ bktC,
    const float* __restrict__ aSc, const float* __restrict__ aDc,
    const ushort* __restrict__ Pc, const float* __restrict__ b3,
    ushort* __restrict__ htb, int N)
{
    const int n = blockIdx.x * 4 + (threadIdx.x >> 6);
    if (n >= N) return;
    const int lane = threadIdx.x & 63;
    const int h  = lane >> 4;          // 16 lanes per head
    const int c4 = lane << 2;          // channel base, 0..252

    float4 out = {0.f, 0.f, 0.f, 0.f};
    gat_phase(n, h, c4, cntA, bktA, aS1, aD1, P1, b1, 0.25f, 1, out);
    gat_phase(n, h, c4, cntB, bktB, aS2, aD2, P2, b2, 0.25f, 1, out);
    gat_phase(n, h, c4, cntC, bktC, aSc, aDc, Pc, b3, 0.50f, 0, out);

    ushort* hp = htb + (size_t)n * 256 + c4;
    const ushort4 hb = *(const ushort4*)hp;
    ushort4 o;
    o.x = f2bf(fmaxf(out.x + bf2f(hb.x), 0.f));
    o.y = f2bf(fmaxf(out.y + bf2f(hb.y), 0.f));
    o.z = f2bf(fmaxf(out.z + bf2f(hb.z), 0.f));
    o.w = f2bf(fmaxf(out.w + bf2f(hb.w), 0.f));
    *(ushort4*)hp = o;
}

// ---------------------------------------------------------------------------
extern "C" void kernel_launch(void* const* d_in, const int* in_sizes, int n_in,
                              void* d_out, int out_size, void* d_ws, size_t ws_size,
                              hipStream_t stream)
{
    const int NT   = in_sizes[0] / 128;
    const int NC   = in_sizes[1] / 64;
    const int E_TT = in_sizes[2] / 2;
    const int E_CT = in_sizes[3];

    const float* x_target = (const float*)d_in[0];
    const float* x_context= (const float*)d_in[1];
    const int*   ei_tt    = (const int*)d_in[2];
    const int*   ei_ct_src= (const int*)d_in[3];
    const int*   ei_ct_dst= (const int*)d_in[4];
    const float* Wt   = (const float*)d_in[5];
    const float* bt   = (const float*)d_in[6];
    const float* Wc   = (const float*)d_in[7];
    const float* bc   = (const float*)d_in[8];
    const float* W_s2d  = (const float*)d_in[9];
    const float* as_s2d = (const float*)d_in[10];
    const float* ad_s2d = (const float*)d_in[11];
    const float* b_s2d  = (const float*)d_in[12];
    const float* W_d2s  = (const float*)d_in[13];
    const float* as_d2s = (const float*)d_in[14];
    const float* ad_d2s = (const float*)d_in[15];
    const float* b_d2s  = (const float*)d_in[16];
    const float* W_ct_src = (const float*)d_in[17];
    const float* W_ct_dst = (const float*)d_in[18];
    const float* as_ct  = (const float*)d_in[19];
    const float* ad_ct  = (const float*)d_in[20];
    const float* b_ct   = (const float*)d_in[21];
    const float* W_out  = (const float*)d_in[22];
    const float* b_out  = (const float*)d_in[23];
    float* out = (float*)d_out;

    const int* tt_src = ei_tt;
    const int* tt_dst = ei_tt + E_TT;

    // ---- workspace carve-up (units: fp32 slots) ----
    float* ws = (float*)d_ws;
    size_t o = 0;
    ushort* htb = (ushort*)(ws + o);   o += (size_t)NT * 128;   // NT*256 bf16
    ushort* Pb1 = (ushort*)(ws + o);   o += (size_t)NT * 128;
    ushort* Pb2 = (ushort*)(ws + o);   o += (size_t)NT * 128;
    ushort* hcb = (ushort*)(ws + o);   o += (size_t)NC * 128;
    ushort* PSb = (ushort*)(ws + o);   o += (size_t)NC * 128;
    ushort* xtb = (ushort*)(ws + o);   o += (size_t)NT * 64;    // NT*128 bf16
    ushort* xcb = (ushort*)(ws + o);   o += (size_t)NC * 32;
    int* bktA = (int*)(ws + o);        o += (size_t)NT * CAP;   // int payload
    int* bktB = (int*)(ws + o);        o += (size_t)NT * CAP;
    int* bktC = (int*)(ws + o);        o += (size_t)NT * CAP;
    float* aS1 = ws + o;               o += (size_t)NT * 4;
    float* aD1 = ws + o;               o += (size_t)NT * 4;
    float* aS2 = ws + o;               o += (size_t)NT * 4;
    float* aD2 = ws + o;               o += (size_t)NT * 4;
    float* aSc = ws + o;               o += (size_t)NT * 4;     // used: NC*4
    float* aDc = ws + o;               o += (size_t)NT * 4;
    int*   cntA = (int*)(ws + o);      o += (size_t)NT;
    int*   cntB = (int*)(ws + o);      o += (size_t)NT;
    int*   cntC = (int*)(ws + o);      o += (size_t)NT;
    float* wfold = ws + o;             o += 1024;
    ushort* WtT   = (ushort*)(ws + o); o += 128 * 256 / 2;
    ushort* WcT   = (ushort*)(ws + o); o += 64 * 256 / 2;
    ushort* Ws2dT = (ushort*)(ws + o); o += 256 * 256 / 2;
    ushort* Wd2sT = (ushort*)(ws + o); o += 256 * 256 / 2;
    ushort* WctsT = (ushort*)(ws + o); o += 256 * 256 / 2;
    ushort* WoutT = (ushort*)(ws + o); o += 256 * 256 / 2;
    (void)ws_size; (void)n_in; (void)out_size;

    const dim3 blk(256);
    const int gGat = (NT + 3) / 4;
    const int RS = (NT + NRANGE - 1) / NRANGE;   // node-range size per XCD
    const int gxT = (NT + 127) / 128;            // 128-row GEMM tiles over NT

    // 1) prep: casts + 6 wtrans + fold_ct + counter zero, one launch
    const int s0 = NT * 32;            // x_target float4 count
    const int s1 = s0 + NC * 16;       // x_context
    const int s2 = s1 + 128 * 256;     // Wt
    const int s3 = s2 + 64 * 256;      // Wc
    const int s4 = s3 + 65536;         // W_s2d
    const int s5 = s4 + 65536;         // W_d2s
    const int s6 = s5 + 65536;         // W_ct_src
    const int s7 = s6 + 65536;         // W_out
    const int s8 = s7 + 1024;          // fold_ct
    const int s9 = s8 + NT * 3;        // counter zero (cntA|cntB|cntC)
    hipLaunchKernelGGL(prep_all, dim3((s9 + 255) / 256), blk, 0, stream,
                       x_target, xtb, x_context, xcb,
                       Wt, WtT, Wc, WcT, W_s2d, Ws2dT, W_d2s, Wd2sT,
                       W_ct_src, WctsT, W_out, WoutT,
                       W_ct_dst, ad_ct, wfold, cntA,
                       s0, s1, s2, s3, s4, s5, s6, s7, s8, s9);

    // 2) topology buckets (standalone, full-device — R11 proven form)
    hipLaunchKernelGGL(build_all_buckets, dim3(1024), blk, 0, stream,
                       tt_src, tt_dst, E_TT, ei_ct_src, ei_ct_dst, E_CT, RS,
                       cntA, bktA, cntB, bktB, cntC, bktC);

    // 3) pretransforms (target + context in one launch)
    hipLaunchKernelGGL(gemm_pre2, dim3(gxT, 8), blk, 0, stream,
                       xtb, WtT, bt, htb, NT, xcb, WcT, bc, hcb, NC);

    // 4) projections + attn dots + ct-dst alphas, one launch
    hipLaunchKernelGGL(gemm_proj3, dim3(gxT, 13), blk, 0, stream,
                       htb, hcb, Ws2dT, Wd2sT, WctsT, Pb1, Pb2, PSb,
                       as_s2d, ad_s2d, as_d2s, ad_d2s, as_ct,
                       aS1, aD1, aS2, aD2, aSc, wfold, aDc, NT, NC);

    // 5) single fused gather: s2d + d2s + ct + skip + relu + bf16 cast
    hipLaunchKernelGGL(gat_gather_fused, dim3(gGat), blk, 0, stream,
                       cntA, bktA, aS1, aD1, Pb1, b_s2d,
                       cntB, bktB, aS2, aD2, Pb2, b_d2s,
                       cntC, bktC, aSc, aDc, PSb, b_ct,
                       htb, NT);

    // 6) final linear
    hipLaunchKernelGGL(gemm_bf16, dim3(gxT, 4), blk, 0, stream,
                       htb, WoutT, b_out, out, nullptr, NT, 256, 0);
}

// Round 12
// 404.135 us; speedup vs baseline: 1.0314x; 1.0012x over previous
//
#include <hip/hip_runtime.h>
#include <hip/hip_bf16.h>
#include <cstdint>
#include <cstddef>

// ---------------------------------------------------------------------------
// STGNN forward. Round 17: dual-output projection GEMM (s2d + d2s fused).
//  - R16 == R13 == 404.5us: rescheduling is exhausted. Session ledger: only
//    WORK/TRAFFIC reductions ever won (R7 fusion -70us, R9 merge -46us).
//    Last untried member of that category: s2d and d2s share A = htb.
//  - gemm_core_dual: stage A-tile once, 16 MFMA/K-step against it (P1 += A@W1,
//    P2 += A@W2), dual attn-dot epilogue. Halves s2d+d2s block count and
//    A-panel traffic. Naive 2-barrier schedule (R12 proved == pipelined),
//    LDS As+B1s+B2s = 20.5KB; + ct-branch pipelined core 30.7KB = 51KB.
//  - alpha branch reads wfold via L2 (no LDS table) to hold 3 blocks/CU.
//  - Everything else byte-identical to R16 (best-of-measured forms).
// ---------------------------------------------------------------------------

#define LRELU_SLOPE 0.2f
#define CAP 64
#define NRANGE 8

typedef __attribute__((ext_vector_type(8))) short short8;
typedef __attribute__((ext_vector_type(4))) float floatx4;

__device__ __forceinline__ float bf2f(ushort u) {
    union { unsigned int u32; float f; } v; v.u32 = ((unsigned int)u) << 16; return v.f;
}
__device__ __forceinline__ ushort f2bf(float x) {
    union { float f; unsigned int u; } v; v.f = x;
    unsigned int r = (v.u + 0x7FFFu + ((v.u >> 16) & 1u)) >> 16;
    return (ushort)r;
}

// ---- prep_all: casts | 6x wtrans | fold_ct | counter zero, one grid --------
__global__ __launch_bounds__(256) void prep_all(
    const float* __restrict__ xt, ushort* __restrict__ xtb,
    const float* __restrict__ xc, ushort* __restrict__ xcb,
    const float* __restrict__ Wt,  ushort* __restrict__ WtT,
    const float* __restrict__ Wc,  ushort* __restrict__ WcT,
    const float* __restrict__ W1,  ushort* __restrict__ W1T,
    const float* __restrict__ W2,  ushort* __restrict__ W2T,
    const float* __restrict__ W3,  ushort* __restrict__ W3T,
    const float* __restrict__ W4,  ushort* __restrict__ W4T,
    const float* __restrict__ Wcd, const float* __restrict__ adc,
    float* __restrict__ wfold, int* __restrict__ cnt0,
    int s0, int s1, int s2, int s3, int s4, int s5, int s6, int s7, int s8,
    int s9)
{
    const int idx = blockIdx.x * blockDim.x + threadIdx.x;
    if (idx < s0) {                       // x_target: float4 -> ushort4
        float4 v = ((const float4*)xt)[idx];
        ushort4 o;
        o.x = f2bf(v.x); o.y = f2bf(v.y); o.z = f2bf(v.z); o.w = f2bf(v.w);
        ((ushort4*)xtb)[idx] = o;
    } else if (idx < s1) {                // x_context
        const int i = idx - s0;
        float4 v = ((const float4*)xc)[i];
        ushort4 o;
        o.x = f2bf(v.x); o.y = f2bf(v.y); o.z = f2bf(v.z); o.w = f2bf(v.w);
        ((ushort4*)xcb)[i] = o;
    } else if (idx < s2) {                // Wt [128][256]
        const int i = idx - s1, k = i >> 8, n = i & 255;
        WtT[n * 128 + k] = f2bf(Wt[i]);
    } else if (idx < s3) {                // Wc [64][256]
        const int i = idx - s2, k = i >> 8, n = i & 255;
        WcT[n * 64 + k] = f2bf(Wc[i]);
    } else if (idx < s4) {                // W_s2d [256][256]
        const int i = idx - s3, k = i >> 8, n = i & 255;
        W1T[n * 256 + k] = f2bf(W1[i]);
    } else if (idx < s5) {                // W_d2s
        const int i = idx - s4, k = i >> 8, n = i & 255;
        W2T[n * 256 + k] = f2bf(W2[i]);
    } else if (idx < s6) {                // W_ct_src
        const int i = idx - s5, k = i >> 8, n = i & 255;
        W3T[n * 256 + k] = f2bf(W3[i]);
    } else if (idx < s7) {                // W_out
        const int i = idx - s6, k = i >> 8, n = i & 255;
        W4T[n * 256 + k] = f2bf(W4[i]);
    } else if (idx < s8) {                // fold_ct: wfold[k,h]
        const int i = idx - s7, k = i >> 2, h = i & 3;
        float s = 0.f;
#pragma unroll 8
        for (int c = 0; c < 64; ++c)
            s += Wcd[(size_t)k * 256 + h * 64 + c] * adc[h * 64 + c];
        wfold[i] = s;
    } else if (idx < s9) {                // zero cntA|cntB|cntC (contiguous)
        cnt0[idx - s8] = 0;
    }
}

// ---- standalone topology bucket build: blocks [0,512) tt, [512,1024) ct ----
// (R11/R13 proven form.) XCD-range-partitioned (range = bx&7), int payload.
__global__ __launch_bounds__(256) void build_all_buckets(
    const int* __restrict__ tt_src, const int* __restrict__ tt_dst, int E_tt,
    const int* __restrict__ ct_src, const int* __restrict__ ct_dst, int E_ct,
    int RS,
    int* __restrict__ cntA, int* __restrict__ bktA,
    int* __restrict__ cntB, int* __restrict__ bktB,
    int* __restrict__ cntC, int* __restrict__ bktC)
{
    const int bx = (blockIdx.x < 512) ? blockIdx.x : blockIdx.x - 512;
    const int range = bx & (NRANGE - 1);
    const int lo = range * RS, hi = lo + RS;
    const int j  = bx >> 3;                  // 64 blocks per range
    const int stride = 64 * blockDim.x;
    if (blockIdx.x < 512) {
        for (int e = j * blockDim.x + threadIdx.x; e < E_tt; e += stride) {
            const int s = tt_src[e], d = tt_dst[e];
            if (d >= lo && d < hi) {
                const int pa = atomicAdd(&cntA[d], 1);
                if (pa < CAP) bktA[(size_t)d * CAP + pa] = s;
            }
            if (s >= lo && s < hi) {
                const int pb = atomicAdd(&cntB[s], 1);
                if (pb < CAP) bktB[(size_t)s * CAP + pb] = d;
            }
        }
    } else {
        for (int e = j * blockDim.x + threadIdx.x; e < E_ct; e += stride) {
            const int s = ct_src[e], d = ct_dst[e];
            if (d >= lo && d < hi) {
                const int p = atomicAdd(&cntC[d], 1);
                if (p < CAP) bktC[(size_t)d * CAP + p] = s;
            }
        }
    }
}

// -------- bf16 MFMA GEMM core, 128x64 tile, double-buffered pipeline --------
// (R13 verbatim.) 4 waves; wave w owns rows 32w..32w+31; one barrier/K-step.
__device__ __forceinline__ void gemm_core(
    const ushort* __restrict__ A, const ushort* __restrict__ Bt,
    const float* __restrict__ bias, float* __restrict__ Cf,
    ushort* __restrict__ Cb, int M, int K, int do_relu,
    const float* __restrict__ attS, const float* __restrict__ attD,
    float* __restrict__ aSo, float* __restrict__ aDo,
    int row0, int col0)
{
    __shared__ short As[2][128][40];  // +8 pad
    __shared__ short Bs[2][64][40];
    const int tid  = threadIdx.x;
    const int ra = tid >> 1;            // A stage: 2 threads/row, 16 cols each
    const int ka = (tid & 1) * 16;
    const int rb = tid >> 2;            // B stage: 4 threads/row, 8 cols each
    const int kb = (tid & 3) * 8;
    const int w    = tid >> 6;
    const int lane = tid & 63;
    const int cix  = lane & 15;
    const int ksel = (lane >> 4) * 8;
    const bool arow_ok = (row0 + ra < M);
    const ushort* aptr = A + (size_t)(row0 + ra) * K + ka;
    const ushort* bptr = Bt + (size_t)(col0 + rb) * K + kb;

    floatx4 acc[2][4];
#pragma unroll
    for (int r = 0; r < 2; ++r)
#pragma unroll
        for (int c = 0; c < 4; ++c) acc[r][c] = (floatx4){0.f, 0.f, 0.f, 0.f};

    // prologue: stage tile 0
    short8 sa0 = {0,0,0,0,0,0,0,0}, sa1 = sa0, sb;
    if (arow_ok) { sa0 = *(const short8*)aptr; sa1 = *(const short8*)(aptr + 8); }
    sb = *(const short8*)bptr;
    *(short8*)&As[0][ra][ka]     = sa0;
    *(short8*)&As[0][ra][ka + 8] = sa1;
    *(short8*)&Bs[0][rb][kb]     = sb;
    __syncthreads();

    int cur = 0;
    for (int k0 = 0; k0 < K; k0 += 32) {
        const bool more = (k0 + 32 < K);
        if (more) {                       // issue t+1 loads (hide under MFMA)
            if (arow_ok) {
                sa0 = *(const short8*)(aptr + k0 + 32);
                sa1 = *(const short8*)(aptr + k0 + 40);
            }
            sb = *(const short8*)(bptr + k0 + 32);
        }
        const short8 af0 = *(const short8*)&As[cur][32 * w + cix][ksel];
        const short8 af1 = *(const short8*)&As[cur][32 * w + 16 + cix][ksel];
#pragma unroll
        for (int c = 0; c < 4; ++c) {
            const short8 bf = *(const short8*)&Bs[cur][16 * c + cix][ksel];
            acc[0][c] = __builtin_amdgcn_mfma_f32_16x16x32_bf16(af0, bf, acc[0][c], 0, 0, 0);
            acc[1][c] = __builtin_amdgcn_mfma_f32_16x16x32_bf16(af1, bf, acc[1][c], 0, 0, 0);
        }
        if (more) {                       // write staged regs to the OTHER buf
            *(short8*)&As[cur ^ 1][ra][ka]     = sa0;
            *(short8*)&As[cur ^ 1][ra][ka + 8] = sa1;
            *(short8*)&Bs[cur ^ 1][rb][kb]     = sb;
        }
        __syncthreads();
        cur ^= 1;
    }

#pragma unroll
    for (int r = 0; r < 2; ++r) {
        const int rbase = row0 + 32 * w + 16 * r + (lane >> 4) * 4;
#pragma unroll
        for (int c = 0; c < 4; ++c) {
            const int col = col0 + 16 * c + cix;
            const float bv = bias ? bias[col] : 0.f;
#pragma unroll
            for (int i = 0; i < 4; ++i) {
                const int row = rbase + i;
                if (row < M) {
                    float v = acc[r][c][i] + bv;
                    if (do_relu) v = fmaxf(v, 0.f);
                    const size_t off = (size_t)row * 256 + col;
                    if (Cf) Cf[off] = v;
                    if (Cb) Cb[off] = f2bf(v);
                }
            }
        }
    }

    // fused per-row attention dots (raw fp32 acc, pre-bias/relu)
    if (attS) {
        float sA[2][4], sD[2][4];
#pragma unroll
        for (int r = 0; r < 2; ++r)
#pragma unroll
            for (int i = 0; i < 4; ++i) { sA[r][i] = 0.f; sD[r][i] = 0.f; }
#pragma unroll
        for (int c = 0; c < 4; ++c) {
            const float as_v = attS[col0 + 16 * c + cix];
            const float ad_v = attD ? attD[col0 + 16 * c + cix] : 0.f;
#pragma unroll
            for (int r = 0; r < 2; ++r)
#pragma unroll
                for (int i = 0; i < 4; ++i) {
                    sA[r][i] += acc[r][c][i] * as_v;
                    sD[r][i] += acc[r][c][i] * ad_v;
                }
        }
#pragma unroll
        for (int off = 1; off < 16; off <<= 1) {
#pragma unroll
            for (int r = 0; r < 2; ++r)
#pragma unroll
                for (int i = 0; i < 4; ++i) {
                    sA[r][i] += __shfl_xor(sA[r][i], off);
                    sD[r][i] += __shfl_xor(sD[r][i], off);
                }
        }
        if (cix == 0) {
            const int head = col0 >> 6;
#pragma unroll
            for (int r = 0; r < 2; ++r) {
                const int rbase = row0 + 32 * w + 16 * r + (lane >> 4) * 4;
#pragma unroll
                for (int i = 0; i < 4; ++i) {
                    const int row = rbase + i;
                    if (row < M) {
                        aSo[(size_t)row * 4 + head] = sA[r][i];
                        if (aDo) aDo[(size_t)row * 4 + head] = sD[r][i];
                    }
                }
            }
        }
    }
}

// ---- dual-output GEMM core: P1 = A@W1, P2 = A@W2 from ONE A-stage ----------
// 128x64 tile per output; naive 2-barrier schedule (R12 == R13 measured);
// 16 MFMA per K-step. Dual attn-dot epilogue (no bias/relu: projections).
__device__ __forceinline__ void gemm_core_dual(
    const ushort* __restrict__ A,
    const ushort* __restrict__ Bt1, const ushort* __restrict__ Bt2,
    ushort* __restrict__ C1, ushort* __restrict__ C2, int M,
    const float* __restrict__ as1v, const float* __restrict__ ad1v,
    const float* __restrict__ as2v, const float* __restrict__ ad2v,
    float* __restrict__ aS1, float* __restrict__ aD1,
    float* __restrict__ aS2, float* __restrict__ aD2,
    int row0, int col0)
{
    __shared__ short Ad[128][40];   // +8 pad
    __shared__ short B1s[64][40];
    __shared__ short B2s[64][40];
    const int tid  = threadIdx.x;
    const int ra = tid >> 1;            // A stage: 2 threads/row, 16 cols each
    const int ka = (tid & 1) * 16;
    const int rb = tid >> 2;            // B stage: 4 threads/row, 8 cols each
    const int kb = (tid & 3) * 8;
    const int w    = tid >> 6;
    const int lane = tid & 63;
    const int cix  = lane & 15;
    const int ksel = (lane >> 4) * 8;
    const bool arow_ok = (row0 + ra < M);
    const ushort* aptr  = A   + (size_t)(row0 + ra) * 256 + ka;
    const ushort* b1ptr = Bt1 + (size_t)(col0 + rb) * 256 + kb;
    const ushort* b2ptr = Bt2 + (size_t)(col0 + rb) * 256 + kb;

    floatx4 acc1[2][4], acc2[2][4];
#pragma unroll
    for (int r = 0; r < 2; ++r)
#pragma unroll
        for (int c = 0; c < 4; ++c) {
            acc1[r][c] = (floatx4){0.f, 0.f, 0.f, 0.f};
            acc2[r][c] = (floatx4){0.f, 0.f, 0.f, 0.f};
        }

    for (int k0 = 0; k0 < 256; k0 += 32) {
        short8 a0 = {0,0,0,0,0,0,0,0}, a1 = a0;
        if (arow_ok) {
            a0 = *(const short8*)(aptr + k0);
            a1 = *(const short8*)(aptr + k0 + 8);
        }
        const short8 b1 = *(const short8*)(b1ptr + k0);
        const short8 b2 = *(const short8*)(b2ptr + k0);
        *(short8*)&Ad[ra][ka]     = a0;
        *(short8*)&Ad[ra][ka + 8] = a1;
        *(short8*)&B1s[rb][kb]    = b1;
        *(short8*)&B2s[rb][kb]    = b2;
        __syncthreads();
        const short8 af0 = *(const short8*)&Ad[32 * w + cix][ksel];
        const short8 af1 = *(const short8*)&Ad[32 * w + 16 + cix][ksel];
#pragma unroll
        for (int c = 0; c < 4; ++c) {
            const short8 bf1 = *(const short8*)&B1s[16 * c + cix][ksel];
            acc1[0][c] = __builtin_amdgcn_mfma_f32_16x16x32_bf16(af0, bf1, acc1[0][c], 0, 0, 0);
            acc1[1][c] = __builtin_amdgcn_mfma_f32_16x16x32_bf16(af1, bf1, acc1[1][c], 0, 0, 0);
            const short8 bf2 = *(const short8*)&B2s[16 * c + cix][ksel];
            acc2[0][c] = __builtin_amdgcn_mfma_f32_16x16x32_bf16(af0, bf2, acc2[0][c], 0, 0, 0);
            acc2[1][c] = __builtin_amdgcn_mfma_f32_16x16x32_bf16(af1, bf2, acc2[1][c], 0, 0, 0);
        }
        __syncthreads();
    }

    // write both outputs (bf16, no bias/relu)
#pragma unroll
    for (int r = 0; r < 2; ++r) {
        const int rbase = row0 + 32 * w + 16 * r + (lane >> 4) * 4;
#pragma unroll
        for (int c = 0; c < 4; ++c) {
            const int col = col0 + 16 * c + cix;
#pragma unroll
            for (int i = 0; i < 4; ++i) {
                const int row = rbase + i;
                if (row < M) {
                    const size_t off = (size_t)row * 256 + col;
                    C1[off] = f2bf(acc1[r][c][i]);
                    C2[off] = f2bf(acc2[r][c][i]);
                }
            }
        }
    }

    // dual fused attention dots
    float sA1[2][4], sD1[2][4], sA2[2][4], sD2[2][4];
#pragma unroll
    for (int r = 0; r < 2; ++r)
#pragma unroll
        for (int i = 0; i < 4; ++i) {
            sA1[r][i] = 0.f; sD1[r][i] = 0.f;
            sA2[r][i] = 0.f; sD2[r][i] = 0.f;
        }
#pragma unroll
    for (int c = 0; c < 4; ++c) {
        const int col = col0 + 16 * c + cix;
        const float a1v = as1v[col], d1v = ad1v[col];
        const float a2v = as2v[col], d2v = ad2v[col];
#pragma unroll
        for (int r = 0; r < 2; ++r)
#pragma unroll
            for (int i = 0; i < 4; ++i) {
                sA1[r][i] += acc1[r][c][i] * a1v;
                sD1[r][i] += acc1[r][c][i] * d1v;
                sA2[r][i] += acc2[r][c][i] * a2v;
                sD2[r][i] += acc2[r][c][i] * d2v;
            }
    }
#pragma unroll
    for (int off = 1; off < 16; off <<= 1) {
#pragma unroll
        for (int r = 0; r < 2; ++r)
#pragma unroll
            for (int i = 0; i < 4; ++i) {
                sA1[r][i] += __shfl_xor(sA1[r][i], off);
                sD1[r][i] += __shfl_xor(sD1[r][i], off);
                sA2[r][i] += __shfl_xor(sA2[r][i], off);
                sD2[r][i] += __shfl_xor(sD2[r][i], off);
            }
    }
    if (cix == 0) {
        const int head = col0 >> 6;
#pragma unroll
        for (int r = 0; r < 2; ++r) {
            const int rbase = row0 + 32 * w + 16 * r + (lane >> 4) * 4;
#pragma unroll
            for (int i = 0; i < 4; ++i) {
                const int row = rbase + i;
                if (row < M) {
                    aS1[(size_t)row * 4 + head] = sA1[r][i];
                    aD1[(size_t)row * 4 + head] = sD1[r][i];
                    aS2[(size_t)row * 4 + head] = sA2[r][i];
                    aD2[(size_t)row * 4 + head] = sD2[r][i];
                }
            }
        }
    }
}

// ---- standalone GEMM (final linear): grid (M/128, 4) -----------------------
__global__ __launch_bounds__(256) void gemm_bf16(
    const ushort* __restrict__ A, const ushort* __restrict__ Bt,
    const float* __restrict__ bias, float* __restrict__ Cf,
    ushort* __restrict__ Cb, int M, int K, int do_relu)
{
    const int row0 = blockIdx.x * 128;
    if (row0 >= M) return;
    gemm_core(A, Bt, bias, Cf, Cb, M, K, do_relu,
              nullptr, nullptr, nullptr, nullptr, row0, blockIdx.y * 64);
}

// ---- merged pretransforms: y<4 target (K=128), y>=4 context (K=64) ---------
__global__ __launch_bounds__(256) void gemm_pre2(
    const ushort* __restrict__ xtb, const ushort* __restrict__ WtT,
    const float* __restrict__ bt, ushort* __restrict__ htb, int NT,
    const ushort* __restrict__ xcb, const ushort* __restrict__ WcT,
    const float* __restrict__ bc, ushort* __restrict__ hcb, int NC)
{
    const int y = blockIdx.y;
    const int row0 = blockIdx.x * 128;
    if (y < 4) {
        if (row0 >= NT) return;
        gemm_core(xtb, WtT, bt, nullptr, htb, NT, 128, 1,
                  nullptr, nullptr, nullptr, nullptr, row0, y * 64);
    } else {
        if (row0 >= NC) return;
        gemm_core(xcb, WcT, bc, nullptr, hcb, NC, 64, 1,
                  nullptr, nullptr, nullptr, nullptr, row0, (y - 4) * 64);
    }
}

// ---- merged projections: y<4 dual s2d+d2s | y<8 ct-src | y==8 alpha --------
__global__ __launch_bounds__(256) void gemm_proj(
    const ushort* __restrict__ htb, const ushort* __restrict__ hcb,
    const ushort* __restrict__ W1T, const ushort* __restrict__ W2T,
    const ushort* __restrict__ W3T,
    ushort* __restrict__ Pb1, ushort* __restrict__ Pb2, ushort* __restrict__ PSb,
    const float* __restrict__ as1, const float* __restrict__ ad1,
    const float* __restrict__ as2, const float* __restrict__ ad2,
    const float* __restrict__ asc,
    float* __restrict__ aS1, float* __restrict__ aD1,
    float* __restrict__ aS2, float* __restrict__ aD2,
    float* __restrict__ aSc,
    const float* __restrict__ wfold, float* __restrict__ aDc,
    int NT, int NC)
{
    const int y = blockIdx.y;
    if (y == 8) {
        // alpha_from_fold, grid-strided; wfold (4KB) read via L2 (no LDS)
        const int total = NT * 4;
        for (int base = blockIdx.x * 256; base < total; base += gridDim.x * 256) {
            const int idx = base + threadIdx.x;
            if (idx < total) {
                const int n = idx >> 2, h = idx & 3;
                const ushort* row = htb + (size_t)n * 256;
                float s = 0.f;
#pragma unroll
                for (int k = 0; k < 256; k += 4) {
                    ushort4 r4 = *(const ushort4*)(row + k);
                    s += bf2f(r4.x) * wfold[(k + 0) * 4 + h] + bf2f(r4.y) * wfold[(k + 1) * 4 + h]
                       + bf2f(r4.z) * wfold[(k + 2) * 4 + h] + bf2f(r4.w) * wfold[(k + 3) * 4 + h];
                }
                aDc[idx] = s;
            }
        }
        return;
    }
    const int row0 = blockIdx.x * 128;
    if (y < 4) {
        if (row0 >= NT) return;
        gemm_core_dual(htb, W1T, W2T, Pb1, Pb2, NT,
                       as1, ad1, as2, ad2, aS1, aD1, aS2, aD2,
                       row0, y * 64);
    } else {
        if (row0 >= NC) return;
        gemm_core(hcb, W3T, nullptr, nullptr, PSb, NC, 256, 0,
                  asc, nullptr, aSc, nullptr, row0, (y - 4) * 64);
    }
}

// ---- one GAT accumulation phase (R7 verbatim; inlined 3x in fused gather) --
__device__ __forceinline__ void gat_phase(
    int n, int h, int c4,
    const int* __restrict__ cnt, const int* __restrict__ bkt,
    const float* __restrict__ aS, const float* __restrict__ aD,
    const ushort* __restrict__ X, const float* __restrict__ bias,
    float scale, int has_self, float4& out)
{
    const float aDn = aD[(size_t)n * 4 + h];
    float4 f = {0.f, 0.f, 0.f, 0.f};
    float den = 0.f;
    if (has_self) {
        float a = aS[(size_t)n * 4 + h] + aDn;
        a = (a >= 0.f) ? a : LRELU_SLOPE * a;
        const float w = __expf(a);
        const ushort4 x = *(const ushort4*)(X + (size_t)n * 256 + c4);
        f.x = w * bf2f(x.x); f.y = w * bf2f(x.y);
        f.z = w * bf2f(x.z); f.w = w * bf2f(x.w);
        den = w;
    }
    const int deg = min(cnt[n], CAP);
    const int* b = bkt + (size_t)n * CAP;
    int i = 0;
    for (; i + 4 <= deg; i += 4) {
        const int s0 = b[i], s1 = b[i + 1], s2 = b[i + 2], s3 = b[i + 3];
        float a0 = aS[(size_t)s0 * 4 + h] + aDn;
        float a1 = aS[(size_t)s1 * 4 + h] + aDn;
        float a2 = aS[(size_t)s2 * 4 + h] + aDn;
        float a3 = aS[(size_t)s3 * 4 + h] + aDn;
        a0 = (a0 >= 0.f) ? a0 : LRELU_SLOPE * a0;
        a1 = (a1 >= 0.f) ? a1 : LRELU_SLOPE * a1;
        a2 = (a2 >= 0.f) ? a2 : LRELU_SLOPE * a2;
        a3 = (a3 >= 0.f) ? a3 : LRELU_SLOPE * a3;
        const float w0 = __expf(a0), w1 = __expf(a1);
        const float w2 = __expf(a2), w3 = __expf(a3);
        const ushort4 x0 = *(const ushort4*)(X + (size_t)s0 * 256 + c4);
        const ushort4 x1 = *(const ushort4*)(X + (size_t)s1 * 256 + c4);
        const ushort4 x2 = *(const ushort4*)(X + (size_t)s2 * 256 + c4);
        const ushort4 x3 = *(const ushort4*)(X + (size_t)s3 * 256 + c4);
        f.x += w0 * bf2f(x0.x) + w1 * bf2f(x1.x) + w2 * bf2f(x2.x) + w3 * bf2f(x3.x);
        f.y += w0 * bf2f(x0.y) + w1 * bf2f(x1.y) + w2 * bf2f(x2.y) + w3 * bf2f(x3.y);
        f.z += w0 * bf2f(x0.z) + w1 * bf2f(x1.z) + w2 * bf2f(x2.z) + w3 * bf2f(x3.z);
        f.w += w0 * bf2f(x0.w) + w1 * bf2f(x1.w) + w2 * bf2f(x2.w) + w3 * bf2f(x3.w);
        den += w0 + w1 + w2 + w3;
    }
    for (; i < deg; ++i) {
        const int s = b[i];
        float a = aS[(size_t)s * 4 + h] + aDn;
        a = (a >= 0.f) ? a : LRELU_SLOPE * a;
        const float w = __expf(a);
        const ushort4 x = *(const ushort4*)(X + (size_t)s * 256 + c4);
        f.x += w * bf2f(x.x); f.y += w * bf2f(x.y);
        f.z += w * bf2f(x.z); f.w += w * bf2f(x.w);
        den += w;
    }
    const float inv = 1.f / fmaxf(den, 1e-16f);
    const float4 bv = *(const float4*)(bias + c4);
    out.x += scale * (f.x * inv + bv.x);
    out.y += scale * (f.y * inv + bv.y);
    out.z += scale * (f.z * inv + bv.z);
    out.w += scale * (f.w * inv + bv.w);
}

// ---- fused gather: all 3 GATs + skip + relu + bf16 cast, one wave/node -----
__global__ __launch_bounds__(256) void gat_gather_fused(
    const int* __restrict__ cntA, const int* __restrict__ bktA,
    const float* __restrict__ aS1, const float* __restrict__ aD1,
    const ushort* __restrict__ P1, const float* __restrict__ b1,
    const int* __restrict__ cntB, const int* __restrict__ bktB,
    const float* __restrict__ aS2, const float* __restrict__ aD2,
    const ushort* __restrict__ P2, const float* __restrict__ b2,
    const int* __restrict__ cntC, const int* __restrict__ bktC,
    const float* __restrict__ aSc, const float* __restrict__ aDc,
    const ushort* __restrict__ Pc, const float* __restrict__ b3,
    ushort* __restrict__ htb, int N)
{
    const int n = blockIdx.x * 4 + (threadIdx.x >> 6);
    if (n >= N) return;
    const int lane = threadIdx.x & 63;
    const int h  = lane >> 4;          // 16 lanes per head
    const int c4 = lane << 2;          // channel base, 0..252

    float4 out = {0.f, 0.f, 0.f, 0.f};
    gat_phase(n, h, c4, cntA, bktA, aS1, aD1, P1, b1, 0.25f, 1, out);
    gat_phase(n, h, c4, cntB, bktB, aS2, aD2, P2, b2, 0.25f, 1, out);
    gat_phase(n, h, c4, cntC, bktC, aSc, aDc, Pc, b3, 0.50f, 0, out);

    ushort* hp = htb + (size_t)n * 256 + c4;
    const ushort4 hb = *(const ushort4*)hp;
    ushort4 o;
    o.x = f2bf(fmaxf(out.x + bf2f(hb.x), 0.f));
    o.y = f2bf(fmaxf(out.y + bf2f(hb.y), 0.f));
    o.z = f2bf(fmaxf(out.z + bf2f(hb.z), 0.f));
    o.w = f2bf(fmaxf(out.w + bf2f(hb.w), 0.f));
    *(ushort4*)hp = o;
}

// ---------------------------------------------------------------------------
extern "C" void kernel_launch(void* const* d_in, const int* in_sizes, int n_in,
                              void* d_out, int out_size, void* d_ws, size_t ws_size,
                              hipStream_t stream)
{
    const int NT   = in_sizes[0] / 128;
    const int NC   = in_sizes[1] / 64;
    const int E_TT = in_sizes[2] / 2;
    const int E_CT = in_sizes[3];

    const float* x_target = (const float*)d_in[0];
    const float* x_context= (const float*)d_in[1];
    const int*   ei_tt    = (const int*)d_in[2];
    const int*   ei_ct_src= (const int*)d_in[3];
    const int*   ei_ct_dst= (const int*)d_in[4];
    const float* Wt   = (const float*)d_in[5];
    const float* bt   = (const float*)d_in[6];
    const float* Wc   = (const float*)d_in[7];
    const float* bc   = (const float*)d_in[8];
    const float* W_s2d  = (const float*)d_in[9];
    const float* as_s2d = (const float*)d_in[10];
    const float* ad_s2d = (const float*)d_in[11];
    const float* b_s2d  = (const float*)d_in[12];
    const float* W_d2s  = (const float*)d_in[13];
    const float* as_d2s = (const float*)d_in[14];
    const float* ad_d2s = (const float*)d_in[15];
    const float* b_d2s  = (const float*)d_in[16];
    const float* W_ct_src = (const float*)d_in[17];
    const float* W_ct_dst = (const float*)d_in[18];
    const float* as_ct  = (const float*)d_in[19];
    const float* ad_ct  = (const float*)d_in[20];
    const float* b_ct   = (const float*)d_in[21];
    const float* W_out  = (const float*)d_in[22];
    const float* b_out  = (const float*)d_in[23];
    float* out = (float*)d_out;

    const int* tt_src = ei_tt;
    const int* tt_dst = ei_tt + E_TT;

    // ---- workspace carve-up (units: fp32 slots) ----
    float* ws = (float*)d_ws;
    size_t o = 0;
    ushort* htb = (ushort*)(ws + o);   o += (size_t)NT * 128;   // NT*256 bf16
    ushort* Pb1 = (ushort*)(ws + o);   o += (size_t)NT * 128;
    ushort* Pb2 = (ushort*)(ws + o);   o += (size_t)NT * 128;
    ushort* hcb = (ushort*)(ws + o);   o += (size_t)NC * 128;
    ushort* PSb = (ushort*)(ws + o);   o += (size_t)NC * 128;
    ushort* xtb = (ushort*)(ws + o);   o += (size_t)NT * 64;    // NT*128 bf16
    ushort* xcb = (ushort*)(ws + o);   o += (size_t)NC * 32;
    int* bktA = (int*)(ws + o);        o += (size_t)NT * CAP;   // int payload
    int* bktB = (int*)(ws + o);        o += (size_t)NT * CAP;
    int* bktC = (int*)(ws + o);        o += (size_t)NT * CAP;
    float* aS1 = ws + o;               o += (size_t)NT * 4;
    float* aD1 = ws + o;               o += (size_t)NT * 4;
    float* aS2 = ws + o;               o += (size_t)NT * 4;
    float* aD2 = ws + o;               o += (size_t)NT * 4;
    float* aSc = ws + o;               o += (size_t)NT * 4;     // used: NC*4
    float* aDc = ws + o;               o += (size_t)NT * 4;
    int*   cntA = (int*)(ws + o);      o += (size_t)NT;
    int*   cntB = (int*)(ws + o);      o += (size_t)NT;
    int*   cntC = (int*)(ws + o);      o += (size_t)NT;
    float* wfold = ws + o;             o += 1024;
    ushort* WtT   = (ushort*)(ws + o); o += 128 * 256 / 2;
    ushort* WcT   = (ushort*)(ws + o); o += 64 * 256 / 2;
    ushort* Ws2dT = (ushort*)(ws + o); o += 256 * 256 / 2;
    ushort* Wd2sT = (ushort*)(ws + o); o += 256 * 256 / 2;
    ushort* WctsT = (ushort*)(ws + o); o += 256 * 256 / 2;
    ushort* WoutT = (ushort*)(ws + o); o += 256 * 256 / 2;
    (void)ws_size; (void)n_in; (void)out_size;

    const dim3 blk(256);
    const int gGat = (NT + 3) / 4;
    const int RS = (NT + NRANGE - 1) / NRANGE;   // node-range size per XCD
    const int gxT = (NT + 127) / 128;            // 128-row GEMM tiles over NT

    // 1) prep: casts + 6 wtrans + fold_ct + counter zero, one launch
    const int s0 = NT * 32;            // x_target float4 count
    const int s1 = s0 + NC * 16;       // x_context
    const int s2 = s1 + 128 * 256;     // Wt
    const int s3 = s2 + 64 * 256;      // Wc
    const int s4 = s3 + 65536;         // W_s2d
    const int s5 = s4 + 65536;         // W_d2s
    const int s6 = s5 + 65536;         // W_ct_src
    const int s7 = s6 + 65536;         // W_out
    const int s8 = s7 + 1024;          // fold_ct
    const int s9 = s8 + NT * 3;        // counter zero (cntA|cntB|cntC)
    hipLaunchKernelGGL(prep_all, dim3((s9 + 255) / 256), blk, 0, stream,
                       x_target, xtb, x_context, xcb,
                       Wt, WtT, Wc, WcT, W_s2d, Ws2dT, W_d2s, Wd2sT,
                       W_ct_src, WctsT, W_out, WoutT,
                       W_ct_dst, ad_ct, wfold, cntA,
                       s0, s1, s2, s3, s4, s5, s6, s7, s8, s9);

    // 2) topology buckets (standalone, full-device — R11 proven form)
    hipLaunchKernelGGL(build_all_buckets, dim3(1024), blk, 0, stream,
                       tt_src, tt_dst, E_TT, ei_ct_src, ei_ct_dst, E_CT, RS,
                       cntA, bktA, cntB, bktB, cntC, bktC);

    // 3) pretransforms (target + context in one launch)
    hipLaunchKernelGGL(gemm_pre2, dim3(gxT, 8), blk, 0, stream,
                       xtb, WtT, bt, htb, NT, xcb, WcT, bc, hcb, NC);

    // 4) projections (dual s2d+d2s | ct) + attn dots + ct-dst alphas
    hipLaunchKernelGGL(gemm_proj, dim3(gxT, 9), blk, 0, stream,
                       htb, hcb, Ws2dT, Wd2sT, WctsT, Pb1, Pb2, PSb,
                       as_s2d, ad_s2d, as_d2s, ad_d2s, as_ct,
                       aS1, aD1, aS2, aD2, aSc, wfold, aDc, NT, NC);

    // 5) single fused gather: s2d + d2s + ct + skip + relu + bf16 cast
    hipLaunchKernelGGL(gat_gather_fused, dim3(gGat), blk, 0, stream,
                       cntA, bktA, aS1, aD1, Pb1, b_s2d,
                       cntB, bktB, aS2, aD2, Pb2, b_d2s,
                       cntC, bktC, aSc, aDc, PSb, b_ct,
                       htb, NT);

    // 6) final linear
    hipLaunchKernelGGL(gemm_bf16, dim3(gxT, 4), blk, 0, stream,
                       htb, WoutT, b_out, out, nullptr, NT, 256, 0);
}